// Round 7
// baseline (535.401 us; speedup 1.0000x reference)
//
#include <hip/hip_runtime.h>
#include <math.h>

#define B_TOT 4096
#define T_LEN 200
#define C_IN  16
#define HH    112
#define NB    16      // batches per block (= MFMA M)
#define EPS   1e-5f
#define SBLK  256     // stats kernel blocks
#define L2E   1.4426950408889634f

typedef _Float16 half8  __attribute__((ext_vector_type(8)));
typedef _Float16 half4v __attribute__((ext_vector_type(4)));
typedef float    f32x4  __attribute__((ext_vector_type(4)));

// Weight split (one-time): fp16 hi + 2^12-scaled fp16 lo, with denormal flush.
__device__ __forceinline__ void split16w(float v, _Float16 &hi, _Float16 &lo) {
    _Float16 h = (_Float16)v;
    float hf = (float)h;
    if (__builtin_fabsf(hf) < 6.103515625e-05f) { h = (_Float16)0.0f; hf = 0.0f; }
    hi = h;
    lo = (_Float16)((v - hf) * 4096.0f);
}

// ---------------- Kernel 1: deterministic per-channel partial sums ----------------
__global__ void stats_kernel(const float* __restrict__ x, float* __restrict__ ws) {
    __shared__ float sm[4][4][8];
    const int tid = threadIdx.x;
    const float4* __restrict__ x4 = (const float4*)x;
    const int total  = B_TOT * T_LEN * C_IN / 4;
    const int stride = SBLK * 256;
    const int i0 = blockIdx.x * 256 + tid;

    float s0=0.f,s1=0.f,s2=0.f,s3=0.f;
    float q0=0.f,q1=0.f,q2=0.f,q3=0.f;
    for (int i = i0; i < total; i += stride) {
        float4 v = x4[i];
        s0 += v.x; q0 += v.x*v.x;
        s1 += v.y; q1 += v.y*v.y;
        s2 += v.z; q2 += v.z*v.z;
        s3 += v.w; q3 += v.w*v.w;
    }
    #pragma unroll
    for (int off = 4; off < 64; off <<= 1) {
        s0 += __shfl_xor(s0, off); q0 += __shfl_xor(q0, off);
        s1 += __shfl_xor(s1, off); q1 += __shfl_xor(q1, off);
        s2 += __shfl_xor(s2, off); q2 += __shfl_xor(q2, off);
        s3 += __shfl_xor(s3, off); q3 += __shfl_xor(q3, off);
    }
    const int lane = tid & 63, wave = tid >> 6;
    if (lane < 4) {
        sm[wave][lane][0] = s0; sm[wave][lane][1] = s1;
        sm[wave][lane][2] = s2; sm[wave][lane][3] = s3;
        sm[wave][lane][4] = q0; sm[wave][lane][5] = q1;
        sm[wave][lane][6] = q2; sm[wave][lane][7] = q3;
    }
    __syncthreads();
    if (tid < 32) {
        const int ch = tid & 15, sq = tid >> 4;
        const int grp = ch >> 2, comp = ch & 3;
        float a = 0.f;
        #pragma unroll
        for (int wv = 0; wv < 4; wv++) a += sm[wv][grp][sq * 4 + comp];
        ws[blockIdx.x * 32 + tid] = a;
    }
}

// ---------------- Kernel 2: MFMA LSTM, K-split balanced wave pairs ----------------
// 256 blocks x 896 threads (14 waves). Wave pair (w, w+7) owns j-tile w:
//   wave w   : K-tiles 0,1 for ALL 4 gates (24 MFMA), owns cell rows r=0,1
//   wave w+7 : K-tiles 2,3 for ALL 4 gates (24 MFMA), owns cell rows r=2,3
// Each wave merges its partials m = ch + cl*2^-12, exchanges the partner's
// two r-rows via ebuf (2x b128 each way), then does a perfectly balanced
// epilogue for its 2 rows. v (=[h;x]*2^12, hi/lo fp16) in LDS A-frag order.
__global__ __launch_bounds__(896, 4) void lstm_kernel(
    const float* __restrict__ x,
    const float* __restrict__ gamma, const float* __restrict__ beta,
    const float* __restrict__ W_ih,  const float* __restrict__ W_hh,
    const float* __restrict__ b_ih,  const float* __restrict__ b_hh,
    const float* __restrict__ W_fc,  const float* __restrict__ b_fc,
    const float* __restrict__ ws,    float* __restrict__ out)
{
    __shared__ float stats_s[32];
    __shared__ float scale_s[16], shift_s[16];
    __shared__ __align__(16) _Float16 vbuf[2][2][4][64][8]; // [plane][hi/lo][kt][lane][8]
    __shared__ __align__(16) float ebuf[7][4][64][4];       // partial-z exchange [jt][r][lane][gate]
    __shared__ __align__(16) float hfinal[NB][HH];

    const int u    = threadIdx.x;
    const int lane = u & 63;
    const int wv   = u >> 6;          // 0..13
    const bool wlow = (wv < 7);
    const int jt   = wlow ? wv : (wv - 7);
    const int nloc = lane & 15;
    const int q    = lane >> 4;       // 0..3
    const int b0   = blockIdx.x * NB;
    const int ktb  = wlow ? 0 : 2;    // this wave's K-tile base
    const int rbase = wlow ? 0 : 2;   // owned cell rows
    const int rpart = wlow ? 2 : 0;   // partner's rows (we publish these)

    // --- BN stats (deterministic fixed-order reduction) ---
    if (u < 32) {
        float a = 0.f;
        for (int blk = 0; blk < SBLK; ++blk) a += ws[blk * 32 + u];
        stats_s[u] = a;
    }
    __syncthreads();
    if (u < 16) {
        const float N = (float)B_TOT * (float)T_LEN;
        const float mean = stats_s[u] / N;
        const float var  = stats_s[16 + u] / N - mean * mean;
        const float sc   = gamma[u] * rsqrtf(var + EPS);
        scale_s[u] = sc;
        shift_s[u] = beta[u] - mean * sc;
    }
    for (int i = u; i < (int)(sizeof(vbuf) / 4); i += 896) ((int*)vbuf)[i] = 0;
    __syncthreads();

    // --- Register-resident weight fragments: all 4 gates, this wave's 2 K-tiles ---
    half8 wHI[4][2], wLO[4][2];
    float bpre[4];
    #pragma unroll
    for (int g = 0; g < 4; ++g) {
        const int n = g * HH + jt * 16 + nloc;
        #pragma unroll
        for (int kk = 0; kk < 2; ++kk) {
            const int kb = (ktb + kk) * 32 + q * 8;   // never straddles k=112
            float wtmp[8];
            if (kb < HH) {
                float4 aa = *(const float4*)&W_hh[n * HH + kb];
                float4 bb = *(const float4*)&W_hh[n * HH + kb + 4];
                wtmp[0]=aa.x; wtmp[1]=aa.y; wtmp[2]=aa.z; wtmp[3]=aa.w;
                wtmp[4]=bb.x; wtmp[5]=bb.y; wtmp[6]=bb.z; wtmp[7]=bb.w;
            } else {
                const int c0 = kb - HH;
                float4 aa = *(const float4*)&W_ih[n * C_IN + c0];
                float4 bb = *(const float4*)&W_ih[n * C_IN + c0 + 4];
                wtmp[0]=aa.x*scale_s[c0+0]; wtmp[1]=aa.y*scale_s[c0+1];
                wtmp[2]=aa.z*scale_s[c0+2]; wtmp[3]=aa.w*scale_s[c0+3];
                wtmp[4]=bb.x*scale_s[c0+4]; wtmp[5]=bb.y*scale_s[c0+5];
                wtmp[6]=bb.z*scale_s[c0+6]; wtmp[7]=bb.w*scale_s[c0+7];
            }
            #pragma unroll
            for (int jj = 0; jj < 8; ++jj) {
                _Float16 th, tl;
                split16w(wtmp[jj], th, tl);
                wHI[g][kk][jj] = th;
                wLO[g][kk][jj] = tl;
            }
        }
        float bb2 = b_ih[n] + b_hh[n];
        #pragma unroll
        for (int c = 0; c < C_IN; ++c) bb2 += W_ih[n * C_IN + c] * shift_s[c];
        bpre[g] = bb2 * ((g == 2) ? (-2.f * L2E) : (-L2E));
    }
    // activation slope constants (2^-12 folded: v in LDS is scaled by 2^12)
    const float k1s = -L2E * (1.f / 4096.f);
    const float k1g = -2.f * L2E * (1.f / 4096.f);

    // --- h write-back mapping (A-fragment address for column jcol) ---
    const int jcol = jt * 16 + nloc;          // 0..111
    const int kt_h = jcol >> 5;
    const int jh   = jcol & 7;
    const int qh16 = ((jcol >> 3) & 3) * 16;  // lane' = row + qh16

    // --- x loader mapping (wave 0): b = u>>2, c = 4*(u&3) ---
    const int xb = u >> 2;
    const int xc = (u & 3) * 4;
    const size_t xbase = (size_t)(b0 + (xb & 15)) * (T_LEN * C_IN) + xc;
    const int jx0 = HH + xc;                  // 112..124 (kt 3 only)
    const int ltx = (xb & 15) + 16 * ((jx0 >> 3) & 3);
    const int jx  = jx0 & 7;

    float4 xreg;
    if (wv == 0) {
        xreg = *(const float4*)&x[xbase];     // x at t=0 -> plane 0
        half4v xh, xl;
        #pragma unroll
        for (int jj = 0; jj < 4; ++jj) {
            const float t = ((const float*)&xreg)[jj] * 4096.f;
            const _Float16 vh = (_Float16)t;
            xh[jj] = vh;
            xl[jj] = (_Float16)((t - (float)vh) * 4096.f);
        }
        *(half4v*)&vbuf[0][0][3][ltx][jx] = xh;
        *(half4v*)&vbuf[0][1][3][ltx][jx] = xl;
    }
    __syncthreads();

    float creg0 = 0.f, creg1 = 0.f;           // cell state for owned rows

    #pragma unroll 2
    for (int step = 0; step < T_LEN; ++step) {
        const int p = step & 1;
        if (wv == 0 && step + 1 < T_LEN)
            xreg = *(const float4*)&x[xbase + (size_t)(step + 1) * C_IN];

        f32x4 ch[4], cl[4];
        #pragma unroll
        for (int g = 0; g < 4; ++g) {
            ch[g] = (f32x4){0.f,0.f,0.f,0.f};
            cl[g] = (f32x4){0.f,0.f,0.f,0.f};
        }
        #pragma unroll
        for (int kk = 0; kk < 2; ++kk) {
            half8 ah = *(const half8*)&vbuf[p][0][ktb + kk][lane][0];
            half8 al = *(const half8*)&vbuf[p][1][ktb + kk][lane][0];
            #pragma unroll
            for (int g = 0; g < 4; ++g) {
                ch[g] = __builtin_amdgcn_mfma_f32_16x16x32_f16(ah, wHI[g][kk], ch[g], 0, 0, 0);
                cl[g] = __builtin_amdgcn_mfma_f32_16x16x32_f16(al, wHI[g][kk], cl[g], 0, 0, 0);
                cl[g] = __builtin_amdgcn_mfma_f32_16x16x32_f16(ah, wLO[g][kk], cl[g], 0, 0, 0);
            }
        }
        // merge hi/lo partials: m = ch + cl*2^-12  (z_true = (m_own+m_partner)*2^-12)
        f32x4 m[4];
        #pragma unroll
        for (int g = 0; g < 4; ++g) {
            #pragma unroll
            for (int r = 0; r < 4; ++r) m[g][r] = fmaf(cl[g][r], 1.f/4096.f, ch[g][r]);
        }
        // publish partner's two rows
        {
            f32x4 e0, e1;
            #pragma unroll
            for (int g = 0; g < 4; ++g) { e0[g] = m[g][rpart]; e1[g] = m[g][rpart + 1]; }
            *(f32x4*)&ebuf[jt][rpart][lane][0]     = e0;
            *(f32x4*)&ebuf[jt][rpart + 1][lane][0] = e1;
        }
        __syncthreads();

        const bool last = (step + 1 == T_LEN);
        {
            f32x4 e0 = *(const f32x4*)&ebuf[jt][rbase][lane][0];
            f32x4 e1 = *(const f32x4*)&ebuf[jt][rbase + 1][lane][0];
            // row 0 of this wave (r = rbase), row 1 (r = rbase+1)
            #pragma unroll
            for (int rr = 0; rr < 2; ++rr) {
                const int r = rbase + rr;
                const f32x4 ee = rr ? e1 : e0;
                float zi = m[0][r] + ee[0];
                float zf = m[1][r] + ee[1];
                float zg = m[2][r] + ee[2];
                float zo = m[3][r] + ee[3];
                const float ai = __builtin_amdgcn_rcpf(1.f + __builtin_amdgcn_exp2f(fmaf(zi, k1s, bpre[0])));
                const float af = __builtin_amdgcn_rcpf(1.f + __builtin_amdgcn_exp2f(fmaf(zf, k1s, bpre[1])));
                const float ag = fmaf(2.f, __builtin_amdgcn_rcpf(1.f + __builtin_amdgcn_exp2f(fmaf(zg, k1g, bpre[2]))), -1.f);
                const float ao = __builtin_amdgcn_rcpf(1.f + __builtin_amdgcn_exp2f(fmaf(zo, k1s, bpre[3])));
                float &cr = rr ? creg1 : creg0;
                const float cn = fmaf(af, cr, ai * ag);
                cr = cn;
                const float e2 = __builtin_amdgcn_exp2f(cn * (-2.f * L2E));
                const float th = fmaf(2.f, __builtin_amdgcn_rcpf(1.f + e2), -1.f);
                const float hv = ao * th;
                if (!last) {
                    const float t = hv * 4096.f;                  // prescaled split
                    const _Float16 vh = (_Float16)t;
                    const _Float16 vl = (_Float16)((t - (float)vh) * 4096.f);
                    vbuf[1 - p][0][kt_h][q * 4 + r + qh16][jh] = vh;
                    vbuf[1 - p][1][kt_h][q * 4 + r + qh16][jh] = vl;
                } else {
                    hfinal[q * 4 + r][jcol] = hv;
                }
            }
        }
        if (wv == 0 && step + 1 < T_LEN) {
            half4v xh, xl;
            #pragma unroll
            for (int jj = 0; jj < 4; ++jj) {
                const float t = ((const float*)&xreg)[jj] * 4096.f;
                const _Float16 vh = (_Float16)t;
                xh[jj] = vh;
                xl[jj] = (_Float16)((t - (float)vh) * 4096.f);
            }
            *(half4v*)&vbuf[1 - p][0][3][ltx][jx] = xh;
            *(half4v*)&vbuf[1 - p][1][3][ltx][jx] = xl;
        }
        __syncthreads();
    }

    // --- FC head ---
    if (u < NB * 6) {
        const int b = u / 6, o = u - b * 6;
        float a = b_fc[o];
        for (int j = 0; j < HH; ++j) a += hfinal[b][j] * W_fc[o * HH + j];
        out[(size_t)(b0 + b) * 6 + o] = tanhf(a);
    }
}

extern "C" void kernel_launch(void* const* d_in, const int* in_sizes, int n_in,
                              void* d_out, int out_size, void* d_ws, size_t ws_size,
                              hipStream_t stream) {
    const float* x     = (const float*)d_in[0];
    const float* gamma = (const float*)d_in[1];
    const float* beta  = (const float*)d_in[2];
    const float* W_ih  = (const float*)d_in[3];
    const float* W_hh  = (const float*)d_in[4];
    const float* b_ih  = (const float*)d_in[5];
    const float* b_hh  = (const float*)d_in[6];
    const float* W_fc  = (const float*)d_in[7];
    const float* b_fc  = (const float*)d_in[8];
    float* out = (float*)d_out;
    float* ws  = (float*)d_ws;

    stats_kernel<<<SBLK, 256, 0, stream>>>(x, ws);
    lstm_kernel<<<B_TOT / NB, 896, 0, stream>>>(x, gamma, beta, W_ih, W_hh,
                                                b_ih, b_hh, W_fc, b_fc, ws, out);
}

// Round 9
// 439.000 us; speedup vs baseline: 1.2196x; 1.2196x over previous
//
#include <hip/hip_runtime.h>
#include <math.h>

#define B_TOT 4096
#define T_LEN 200
#define C_IN  16
#define HH    112
#define NB    16      // batches per block (= MFMA M)
#define EPS   1e-5f
#define SBLK  256     // stats kernel blocks
#define L2E   1.4426950408889634f

typedef _Float16 half8  __attribute__((ext_vector_type(8)));
typedef _Float16 half4v __attribute__((ext_vector_type(4)));
typedef float    f32x4  __attribute__((ext_vector_type(4)));

// Weight split (one-time): fp16 hi + 2^12-scaled fp16 lo, with denormal flush.
__device__ __forceinline__ void split16w(float v, _Float16 &hi, _Float16 &lo) {
    _Float16 h = (_Float16)v;
    float hf = (float)h;
    if (__builtin_fabsf(hf) < 6.103515625e-05f) { h = (_Float16)0.0f; hf = 0.0f; }
    hi = h;
    lo = (_Float16)((v - hf) * 4096.0f);
}

// ---------------- Kernel 1: deterministic per-channel partial sums ----------------
__global__ void stats_kernel(const float* __restrict__ x, float* __restrict__ ws) {
    __shared__ float sm[4][4][8];
    const int tid = threadIdx.x;
    const float4* __restrict__ x4 = (const float4*)x;
    const int total  = B_TOT * T_LEN * C_IN / 4;
    const int stride = SBLK * 256;
    const int i0 = blockIdx.x * 256 + tid;

    float s0=0.f,s1=0.f,s2=0.f,s3=0.f;
    float q0=0.f,q1=0.f,q2=0.f,q3=0.f;
    for (int i = i0; i < total; i += stride) {
        float4 v = x4[i];
        s0 += v.x; q0 += v.x*v.x;
        s1 += v.y; q1 += v.y*v.y;
        s2 += v.z; q2 += v.z*v.z;
        s3 += v.w; q3 += v.w*v.w;
    }
    #pragma unroll
    for (int off = 4; off < 64; off <<= 1) {
        s0 += __shfl_xor(s0, off); q0 += __shfl_xor(q0, off);
        s1 += __shfl_xor(s1, off); q1 += __shfl_xor(q1, off);
        s2 += __shfl_xor(s2, off); q2 += __shfl_xor(q2, off);
        s3 += __shfl_xor(s3, off); q3 += __shfl_xor(q3, off);
    }
    const int lane = tid & 63, wave = tid >> 6;
    if (lane < 4) {
        sm[wave][lane][0] = s0; sm[wave][lane][1] = s1;
        sm[wave][lane][2] = s2; sm[wave][lane][3] = s3;
        sm[wave][lane][4] = q0; sm[wave][lane][5] = q1;
        sm[wave][lane][6] = q2; sm[wave][lane][7] = q3;
    }
    __syncthreads();
    if (tid < 32) {
        const int ch = tid & 15, sq = tid >> 4;
        const int grp = ch >> 2, comp = ch & 3;
        float a = 0.f;
        #pragma unroll
        for (int wv = 0; wv < 4; wv++) a += sm[wv][grp][sq * 4 + comp];
        ws[blockIdx.x * 32 + tid] = a;
    }
}

// ---------------- Kernel 2: MFMA LSTM, barrier-free dataflow ----------------
// 256 blocks x 448 threads (7 waves). Wave w owns j-tile w, ALL 4 gates
// (48 MFMAs: ch 4-chains, ca/cb split 4-chains), in-lane cell epilogue.
// NO per-step barrier: per-wave sequence flags (lag-1 producer waits) let
// leader waves' MFMAs of step t+1 overlap laggards' epilogue of step t.
// 2-plane vbuf is provably safe under the flag protocol (skew <= 1 step).
__global__ __launch_bounds__(448, 2) void lstm_kernel(
    const float* __restrict__ x,
    const float* __restrict__ gamma, const float* __restrict__ beta,
    const float* __restrict__ W_ih,  const float* __restrict__ W_hh,
    const float* __restrict__ b_ih,  const float* __restrict__ b_hh,
    const float* __restrict__ W_fc,  const float* __restrict__ b_fc,
    const float* __restrict__ ws,    float* __restrict__ out)
{
    __shared__ float stats_s[32];
    __shared__ float scale_s[16], shift_s[16];
    __shared__ __align__(16) _Float16 vbuf[2][2][4][64][8]; // [plane][hi/lo][kt][lane][8]
    __shared__ int sflag[8];
    __shared__ __align__(16) float hfinal[NB][HH];

    const int u    = threadIdx.x;
    const int lane = u & 63;
    const int wv   = u >> 6;          // wave = j-tile 0..6
    const int nloc = lane & 15;
    const int q    = lane >> 4;       // 0..3
    const int b0   = blockIdx.x * NB;

    // --- BN stats (deterministic fixed-order reduction) ---
    if (u < 32) {
        float a = 0.f;
        for (int blk = 0; blk < SBLK; ++blk) a += ws[blk * 32 + u];
        stats_s[u] = a;
    }
    if (u >= 32 && u < 40) sflag[u - 32] = 0;
    __syncthreads();
    if (u < 16) {
        const float N = (float)B_TOT * (float)T_LEN;
        const float mean = stats_s[u] / N;
        const float var  = stats_s[16 + u] / N - mean * mean;
        const float sc   = gamma[u] * rsqrtf(var + EPS);
        scale_s[u] = sc;
        shift_s[u] = beta[u] - mean * sc;
    }
    for (int i = u; i < (int)(sizeof(vbuf) / 4); i += 448) ((int*)vbuf)[i] = 0;
    __syncthreads();

    // --- Register-resident weight fragments: 4 gates x 4 kt, hi/lo ---
    half8 wHI[4][4], wLO[4][4];
    float bpre[4];
    #pragma unroll
    for (int g = 0; g < 4; ++g) {
        const int n = g * HH + wv * 16 + nloc;
        #pragma unroll
        for (int kt = 0; kt < 4; ++kt) {
            const int kb = kt * 32 + q * 8;    // never straddles k=112
            float wtmp[8];
            if (kb < HH) {
                float4 aa = *(const float4*)&W_hh[n * HH + kb];
                float4 bb = *(const float4*)&W_hh[n * HH + kb + 4];
                wtmp[0]=aa.x; wtmp[1]=aa.y; wtmp[2]=aa.z; wtmp[3]=aa.w;
                wtmp[4]=bb.x; wtmp[5]=bb.y; wtmp[6]=bb.z; wtmp[7]=bb.w;
            } else {
                const int c0 = kb - HH;
                float4 aa = *(const float4*)&W_ih[n * C_IN + c0];
                float4 bb = *(const float4*)&W_ih[n * C_IN + c0 + 4];
                wtmp[0]=aa.x*scale_s[c0+0]; wtmp[1]=aa.y*scale_s[c0+1];
                wtmp[2]=aa.z*scale_s[c0+2]; wtmp[3]=aa.w*scale_s[c0+3];
                wtmp[4]=bb.x*scale_s[c0+4]; wtmp[5]=bb.y*scale_s[c0+5];
                wtmp[6]=bb.z*scale_s[c0+6]; wtmp[7]=bb.w*scale_s[c0+7];
            }
            #pragma unroll
            for (int jj = 0; jj < 8; ++jj) {
                _Float16 th, tl;
                split16w(wtmp[jj], th, tl);
                wHI[g][kt][jj] = th;
                wLO[g][kt][jj] = tl;
            }
        }
        float bb2 = b_ih[n] + b_hh[n];
        #pragma unroll
        for (int c = 0; c < C_IN; ++c) bb2 += W_ih[n * C_IN + c] * shift_s[c];
        bpre[g] = bb2 * ((g == 2) ? (-2.f * L2E) : (-L2E));
    }
    const float k1s = -L2E * (1.f / 4096.f);        // sigmoid slope (4096-prescaled acc)
    const float k1g = -2.f * L2E * (1.f / 4096.f);  // tanh slope

    // --- h write-back mapping (A-fragment address for column jcol) ---
    const int jcol = wv * 16 + nloc;          // 0..111
    const int kt_h = jcol >> 5;
    const int jh   = jcol & 7;
    const int qh16 = ((jcol >> 3) & 3) * 16;  // lane' = batchrow + qh16

    // --- x loader mapping (wave 0): b = u>>2, c = 4*(u&3) ---
    const int xb = u >> 2;
    const int xc = (u & 3) * 4;
    const size_t xbase = (size_t)(b0 + (xb & 15)) * (T_LEN * C_IN) + xc;
    const int jx0 = HH + xc;                  // 112..124 (kt 3 only)
    const int ltx = (xb & 15) + 16 * ((jx0 >> 3) & 3);
    const int jx  = jx0 & 7;

    float4 xreg;
    if (wv == 0) {
        xreg = *(const float4*)&x[xbase];     // x at t=0 -> plane 0
        half4v xh, xl;
        #pragma unroll
        for (int jj = 0; jj < 4; ++jj) {
            const float t = ((const float*)&xreg)[jj] * 4096.f;
            const _Float16 vh = (_Float16)t;
            xh[jj] = vh;
            xl[jj] = (_Float16)((t - (float)vh) * 4096.f);
        }
        *(half4v*)&vbuf[0][0][3][ltx][jx] = xh;
        *(half4v*)&vbuf[0][1][3][ltx][jx] = xl;
    }
    __syncthreads();

    float creg[4] = {0.f, 0.f, 0.f, 0.f};
    volatile int* vf = sflag;

    // seed anti-phase: stagger wave entry by ~wv*256 cycles
    for (int i = 0; i < wv; ++i) __builtin_amdgcn_s_sleep(4);

    #pragma unroll 2
    for (int step = 0; step < T_LEN; ++step) {
        const int p = step & 1;

        // wait for all producers of v(step) (lag-1; does NOT sync consumers)
        for (;;) {
            bool ok = true;
            #pragma unroll
            for (int i = 0; i < 7; ++i) ok &= (vf[i] >= step);
            if (ok) break;
        }
        __threadfence_block();

        if (wv == 0 && step + 1 < T_LEN)
            xreg = *(const float4*)&x[xbase + (size_t)(step + 1) * C_IN];

        __builtin_amdgcn_s_setprio(1);
        half8 ah[4], al[4];
        #pragma unroll
        for (int kt = 0; kt < 4; ++kt) {
            ah[kt] = *(const half8*)&vbuf[p][0][kt][lane][0];
            al[kt] = *(const half8*)&vbuf[p][1][kt][lane][0];
        }
        f32x4 ch[4], ca[4], cb[4];
        #pragma unroll
        for (int g = 0; g < 4; ++g) {
            ch[g] = (f32x4){0.f,0.f,0.f,0.f};
            ca[g] = (f32x4){0.f,0.f,0.f,0.f};
            cb[g] = (f32x4){0.f,0.f,0.f,0.f};
        }
        #pragma unroll
        for (int kt = 0; kt < 4; ++kt) {
            #pragma unroll
            for (int g = 0; g < 4; ++g) {
                ch[g] = __builtin_amdgcn_mfma_f32_16x16x32_f16(ah[kt], wHI[g][kt], ch[g], 0, 0, 0);
                ca[g] = __builtin_amdgcn_mfma_f32_16x16x32_f16(al[kt], wHI[g][kt], ca[g], 0, 0, 0);
                cb[g] = __builtin_amdgcn_mfma_f32_16x16x32_f16(ah[kt], wLO[g][kt], cb[g], 0, 0, 0);
            }
        }
        __builtin_amdgcn_s_setprio(0);

        // --- in-lane epilogue: D[row=q*4+r][col=jcol], 4 cells/lane ---
        const bool last = (step + 1 == T_LEN);
        #pragma unroll
        for (int r = 0; r < 4; ++r) {
            const float m0 = fmaf(ca[0][r] + cb[0][r], 1.f/4096.f, ch[0][r]);
            const float m1 = fmaf(ca[1][r] + cb[1][r], 1.f/4096.f, ch[1][r]);
            const float m2 = fmaf(ca[2][r] + cb[2][r], 1.f/4096.f, ch[2][r]);
            const float m3 = fmaf(ca[3][r] + cb[3][r], 1.f/4096.f, ch[3][r]);
            const float ai = __builtin_amdgcn_rcpf(1.f + __builtin_amdgcn_exp2f(fmaf(m0, k1s, bpre[0])));
            const float af = __builtin_amdgcn_rcpf(1.f + __builtin_amdgcn_exp2f(fmaf(m1, k1s, bpre[1])));
            const float ag = fmaf(2.f, __builtin_amdgcn_rcpf(1.f + __builtin_amdgcn_exp2f(fmaf(m2, k1g, bpre[2]))), -1.f);
            const float ao = __builtin_amdgcn_rcpf(1.f + __builtin_amdgcn_exp2f(fmaf(m3, k1s, bpre[3])));
            const float cn = fmaf(af, creg[r], ai * ag);
            creg[r] = cn;
            const float e2 = __builtin_amdgcn_exp2f(cn * (-2.f * L2E));
            const float th = fmaf(2.f, __builtin_amdgcn_rcpf(1.f + e2), -1.f);
            const float hv = ao * th;
            if (!last) {
                const float t = hv * 4096.f;                 // prescaled split
                const _Float16 vh = (_Float16)t;
                const _Float16 vl = (_Float16)((t - (float)vh) * 4096.f);
                vbuf[1 - p][0][kt_h][q * 4 + r + qh16][jh] = vh;
                vbuf[1 - p][1][kt_h][q * 4 + r + qh16][jh] = vl;
            } else {
                hfinal[q * 4 + r][jcol] = hv;
            }
        }
        if (wv == 0 && step + 1 < T_LEN) {
            half4v xh, xl;
            #pragma unroll
            for (int jj = 0; jj < 4; ++jj) {
                const float t = ((const float*)&xreg)[jj] * 4096.f;
                const _Float16 vh = (_Float16)t;
                xh[jj] = vh;
                xl[jj] = (_Float16)((t - (float)vh) * 4096.f);
            }
            *(half4v*)&vbuf[1 - p][0][3][ltx][jx] = xh;
            *(half4v*)&vbuf[1 - p][1][3][ltx][jx] = xl;
        }
        // publish: all v(step+1) contributions from this wave are committed
        if (step + 1 < T_LEN) {
            __threadfence_block();
            if (lane == 0) sflag[wv] = step + 1;
        }
    }
    __syncthreads();

    // --- FC head ---
    if (u < NB * 6) {
        const int b = u / 6, o = u - b * 6;
        float a = b_fc[o];
        for (int j = 0; j < HH; ++j) a += hfinal[b][j] * W_fc[o * HH + j];
        out[(size_t)(b0 + b) * 6 + o] = tanhf(a);
    }
}

extern "C" void kernel_launch(void* const* d_in, const int* in_sizes, int n_in,
                              void* d_out, int out_size, void* d_ws, size_t ws_size,
                              hipStream_t stream) {
    const float* x     = (const float*)d_in[0];
    const float* gamma = (const float*)d_in[1];
    const float* beta  = (const float*)d_in[2];
    const float* W_ih  = (const float*)d_in[3];
    const float* W_hh  = (const float*)d_in[4];
    const float* b_ih  = (const float*)d_in[5];
    const float* b_hh  = (const float*)d_in[6];
    const float* W_fc  = (const float*)d_in[7];
    const float* b_fc  = (const float*)d_in[8];
    float* out = (float*)d_out;
    float* ws  = (float*)d_ws;

    stats_kernel<<<SBLK, 256, 0, stream>>>(x, ws);
    lstm_kernel<<<B_TOT / NB, 448, 0, stream>>>(x, gamma, beta, W_ih, W_hh,
                                                b_ih, b_hh, W_fc, b_fc, ws, out);
}